// Round 1
// baseline (373.657 us; speedup 1.0000x reference)
//
#include <hip/hip_runtime.h>
#include <math.h>

#define NFFT 2048
#define HOP 512
#define NFREQ 1025
#define NB 8
#define NT 2048
#define HALF 1024
#define PAD 1024
#define ORIG_LEN 1048064

// ---------------- K1: per-frame irfft(2048) via 1024-pt complex inverse FFT ----------------
// One block (256 threads) per frame (b,t). LDS: 1024 complex work array + 512 twiddles.
__global__ __launch_bounds__(256) void istft_fft_kernel(const float* __restrict__ in,
                                                        float* __restrict__ contrib) {
    __shared__ float2 data[HALF];     // 8 KB
    __shared__ float2 tw[HALF / 2];   // 4 KB, tw[r] = e^{+2pi i r/1024}
    const int tid = threadIdx.x;

    // XCD-chunked swizzle: 16384 blocks, 8 XCDs -> each XCD gets a contiguous 2048-frame chunk
    unsigned bid = blockIdx.x;
    unsigned nwg = gridDim.x;
    unsigned wid = (bid & 7u) * (nwg >> 3) + (bid >> 3);
    const int b = wid >> 11;        // wid / 2048
    const int t = wid & 2047;       // wid % 2048

    // twiddle table (inverse transform: +sin)
    for (int r = tid; r < HALF / 2; r += 256) {
        float s, c;
        sincosf(6.28318530717958647692f * (float)r * (1.0f / 1024.0f), &s, &c);
        tw[r] = make_float2(c, s);
    }

    // Pack: Z'_k = A_k + i B_k, stored bit-reversed.
    // A_k = X_k + conj(X_{1024-k});  B_k = (X_k - conj(X_{1024-k})) * e^{+i pi k/1024}
    // X_0 and X_1024 treated as real (reference multiplies their Im by sin(0)=0).
    const float* base = in + (size_t)b * NFREQ * (NT * 2) + (size_t)t * 2;
#pragma unroll
    for (int kk = 0; kk < 4; ++kk) {
        const int k = tid + kk * 256;
        float2 xa = *(const float2*)(base + (size_t)k * (NT * 2));
        float2 xb = *(const float2*)(base + (size_t)(1024 - k) * (NT * 2));
        float2 X, Xc;
        if (k == 0) { X = make_float2(xa.x, 0.0f); Xc = make_float2(xb.x, 0.0f); }
        else        { X = xa;                      Xc = make_float2(xb.x, -xb.y); }
        const float ar = X.x + Xc.x, ai = X.y + Xc.y;
        const float dr = X.x - Xc.x, di = X.y - Xc.y;
        float s, c;
        sincosf(3.14159265358979323846f * (float)k * (1.0f / 1024.0f), &s, &c);
        const float br = dr * c - di * s;
        const float bi = dr * s + di * c;
        const int rk = (int)(__brev((unsigned)k) >> 22);   // 10-bit bit-reverse
        data[rk] = make_float2(ar - bi, ai + br);          // A + iB
    }
    __syncthreads();

    // 10 radix-2 DIT stages, in place, e^{+} twiddles (inverse direction)
    for (int len = 2; len <= HALF; len <<= 1) {
        const int half = len >> 1;
        const int tstep = HALF / len;
#pragma unroll
        for (int ii = 0; ii < 2; ++ii) {
            const int i = tid + ii * 256;                  // 512 butterflies/stage
            const int grp = i / half;
            const int pos = i - grp * half;
            const int i0 = grp * len + pos;
            const int i1 = i0 + half;
            const float2 w = tw[pos * tstep];
            const float2 u = data[i0];
            const float2 v = data[i1];
            const float tr = v.x * w.x - v.y * w.y;
            const float ti = v.x * w.y + v.y * w.x;
            data[i0] = make_float2(u.x + tr, u.y + ti);
            data[i1] = make_float2(u.x - tr, u.y - ti);
        }
        __syncthreads();
    }

    // z_m = S_m / 2048; x_{2m} = Re z_m, x_{2m+1} = Im z_m -> contiguous float2 store
    float2* row = (float2*)(contrib + (size_t)wid * NFFT);
    const float sc = 1.0f / 2048.0f;
#pragma unroll
    for (int mm = 0; mm < 4; ++mm) {
        const int m = tid + mm * 256;
        const float2 z = data[m];
        row[m] = make_float2(z.x * sc, z.y * sc);
    }
}

// ---------------- K2: overlap-add + envelope normalize + trim ----------------
__global__ __launch_bounds__(256) void ola_kernel(const float* __restrict__ contrib,
                                                  const float* __restrict__ wsq,
                                                  float* __restrict__ out) {
    const unsigned j = blockIdx.x * 256u + threadIdx.x;
    if (j >= (unsigned)NB * (unsigned)ORIG_LEN) return;
    const int b = (int)(j / (unsigned)ORIG_LEN);
    const int p = (int)(j % (unsigned)ORIG_LEN);
    const int l = p + PAD;                         // position in padded audio

    int t_lo = (l - 1536) >> 9;                    // floor((l-2047)/512) via floor((l-1536)/512)
    if (t_lo < 0) t_lo = 0;
    int t_hi = l >> 9;
    if (t_hi > NT - 1) t_hi = NT - 1;

    float acc = 0.0f, wacc = 0.0f;
    const float* crow = contrib + (size_t)b * NT * NFFT;
    for (int t = t_lo; t <= t_hi; ++t) {
        const int n = l - (t << 9);                // 0 <= n < 2048
        acc  += crow[(size_t)t * NFFT + n];
        wacc += wsq[n];
    }
    out[j] = acc / fmaxf(wacc, 1e-8f);
}

extern "C" void kernel_launch(void* const* d_in, const int* in_sizes, int n_in,
                              void* d_out, int out_size, void* d_ws, size_t ws_size,
                              hipStream_t stream) {
    const float* stft = (const float*)d_in[0];   // [8,1025,2048,2] f32
    // d_in[1] = DFT kernel matrix (unused: FFT reproduces it exactly)
    const float* wsq  = (const float*)d_in[2];   // [2048] f32
    float* contrib = (float*)d_ws;               // [8,2048,2048] f32 = 128 MiB scratch
    float* out = (float*)d_out;                  // [8,1048064] f32

    istft_fft_kernel<<<NB * NT, 256, 0, stream>>>(stft, contrib);

    const unsigned total = (unsigned)NB * (unsigned)ORIG_LEN;   // 8,384,512
    ola_kernel<<<(total + 255u) / 256u, 256, 0, stream>>>(contrib, wsq, out);
}

// Round 2
// 365.041 us; speedup vs baseline: 1.0236x; 1.0236x over previous
//
#include <hip/hip_runtime.h>
#include <math.h>

#define NFREQ 1025
#define NT 2048
#define NFFT 2048
#define HOP 512
#define NB 8
#define ORIG_LEN 1048064
#define NSEG 2047   // output segments per batch: s = 2..2048

// XOR swizzle for the data arrays: bijective on [0,1024), keeps 4-float groups
// contiguous & 16B-aligned, spreads power-of-2 strides across banks.
__device__ __forceinline__ int dphys(int m) {
    return m ^ ((((m >> 5) ^ (m >> 8)) & 7) << 2);
}
// additive pad for the twiddle table (scalar reads only)
__device__ __forceinline__ int tphys(int r) { return r + (r >> 4); }

// ---------------- K1: per-frame irfft(2048) via 1024-pt radix-4 inverse FFT ----------------
__global__ __launch_bounds__(256) void istft_fft_kernel(const float* __restrict__ in,
                                                        float* __restrict__ contrib) {
    __shared__ __align__(16) float R[1024];
    __shared__ __align__(16) float I[1024];
    __shared__ float TWR[816], TWI[816];
    const int tid = threadIdx.x;
    unsigned bid = blockIdx.x, nwg = gridDim.x;
    unsigned wid = (bid & 7u) * (nwg >> 3) + (bid >> 3);   // XCD-chunked swizzle
    const int b = (int)(wid >> 11), t = (int)(wid & 2047u);

    // TW[r] = e^{+2pi i r/1024}, r in [0,768)
    for (int r = tid; r < 768; r += 256) {
        float s, c;
        sincosf(6.28318530717958647692f * (float)r * (1.0f / 1024.0f), &s, &c);
        const int pr = tphys(r);
        TWR[pr] = c; TWI[pr] = s;
    }

    // ---- pack (real-FFT fold) + radix-4 stage 1 (twiddle-free) in registers ----
    const float* base = in + (size_t)b * NFREQ * (NT * 2) + (size_t)t * 2;
    float vr[4], vi[4];
#pragma unroll
    for (int kk = 0; kk < 4; ++kk) {
        const int k = tid + (kk << 8);
        const float2 xa = *(const float2*)(base + (size_t)k * (NT * 2));
        const float2 xb = *(const float2*)(base + (size_t)(1024 - k) * (NT * 2));
        float Xr, Xi, Cr, Ci;
        if (k == 0) { Xr = xa.x; Xi = 0.0f; Cr = xb.x; Ci = 0.0f; }
        else        { Xr = xa.x; Xi = xa.y; Cr = xb.x; Ci = -xb.y; }
        const float ar = Xr + Cr, ai = Xi + Ci;
        const float dr = Xr - Cr, di = Xi - Ci;
        float s, c;
        sincosf(3.14159265358979323846f * (float)k * (1.0f / 1024.0f), &s, &c);
        const float br = dr * c - di * s;
        const float bi = dr * s + di * c;
        vr[kk] = (ar - bi) * (1.0f / 2048.0f);   // fold 1/N scale here
        vi[kk] = (ai + br) * (1.0f / 2048.0f);
    }
    // thread's 4 values are one digit-reversed radix-4 group g = rev8(tid), member j = kk
    {
        const float y0r = vr[0] + vr[1] + vr[2] + vr[3];
        const float y0i = vi[0] + vi[1] + vi[2] + vi[3];
        const float y1r = vr[0] - vi[1] - vr[2] + vi[3];
        const float y1i = vi[0] + vr[1] - vi[2] - vr[3];
        const float y2r = vr[0] - vr[1] + vr[2] - vr[3];
        const float y2i = vi[0] - vi[1] + vi[2] - vi[3];
        const float y3r = vr[0] + vi[1] - vr[2] - vi[3];
        const float y3i = vi[0] - vr[1] - vi[2] + vr[3];
        const int g = ((tid & 3) << 6) | (((tid >> 2) & 3) << 4) |
                      (((tid >> 4) & 3) << 2) | ((tid >> 6) & 3);
        const int p4 = dphys(g << 2);
        *(float4*)&R[p4] = make_float4(y0r, y1r, y2r, y3r);
        *(float4*)&I[p4] = make_float4(y0i, y1i, y2i, y3i);
    }
    __syncthreads();

    // ---- radix-4 stages 2..4 (LEN = 16, 64, 256): wave-local, no barriers ----
#define STAGE(LEN) { \
        const int quarter = (LEN) >> 2; \
        const int tstep = 1024 / (LEN); \
        const int gg = tid / quarter, pp = tid % quarter; \
        const int i0 = gg * (LEN) + pp; \
        const int ia = dphys(i0), ib = dphys(i0 + quarter); \
        const int ic = dphys(i0 + 2 * quarter), id = dphys(i0 + 3 * quarter); \
        const float arr = R[ia], ari = I[ia]; \
        const float brr = R[ib], bri = I[ib]; \
        const float crr = R[ic], cri = I[ic]; \
        const float drr = R[id], dri = I[id]; \
        const int j1 = tphys(pp * tstep), j2 = tphys(2 * pp * tstep), j3 = tphys(3 * pp * tstep); \
        const float w1r = TWR[j1], w1i = TWI[j1]; \
        const float w2r = TWR[j2], w2i = TWI[j2]; \
        const float w3r = TWR[j3], w3i = TWI[j3]; \
        const float t1r = brr * w1r - bri * w1i, t1i = brr * w1i + bri * w1r; \
        const float t2r = crr * w2r - cri * w2i, t2i = crr * w2i + cri * w2r; \
        const float t3r = drr * w3r - dri * w3i, t3i = drr * w3i + dri * w3r; \
        R[ia] = arr + t1r + t2r + t3r;  I[ia] = ari + t1i + t2i + t3i; \
        R[ib] = arr - t1i - t2r + t3i;  I[ib] = ari + t1r - t2i - t3r; \
        R[ic] = arr - t1r + t2r - t3r;  I[ic] = ari - t1i + t2i - t3i; \
        R[id] = arr + t1i - t2r - t3i;  I[id] = ari - t1r - t2i + t3r; \
    }
    STAGE(16)
    STAGE(64)
    STAGE(256)
#undef STAGE
    __syncthreads();

    // ---- stage 5 (LEN=1024) fused with the global store ----
    {
        const int pp = tid;
        const int ia = dphys(pp), ib = dphys(pp + 256);
        const int ic = dphys(pp + 512), id = dphys(pp + 768);
        const float arr = R[ia], ari = I[ia];
        const float brr = R[ib], bri = I[ib];
        const float crr = R[ic], cri = I[ic];
        const float drr = R[id], dri = I[id];
        const int j1 = tphys(pp), j2 = tphys(2 * pp), j3 = tphys(3 * pp);
        const float w1r = TWR[j1], w1i = TWI[j1];
        const float w2r = TWR[j2], w2i = TWI[j2];
        const float w3r = TWR[j3], w3i = TWI[j3];
        const float t1r = brr * w1r - bri * w1i, t1i = brr * w1i + bri * w1r;
        const float t2r = crr * w2r - cri * w2i, t2i = crr * w2i + cri * w2r;
        const float t3r = drr * w3r - dri * w3i, t3i = drr * w3i + dri * w3r;
        float2* row = (float2*)(contrib + (size_t)wid * NFFT);
        row[pp]       = make_float2(arr + t1r + t2r + t3r, ari + t1i + t2i + t3i);
        row[pp + 256] = make_float2(arr - t1i - t2r + t3i, ari + t1r - t2i - t3r);
        row[pp + 512] = make_float2(arr - t1r + t2r - t3r, ari - t1i + t2i - t3i);
        row[pp + 768] = make_float2(arr + t1i - t2r - t3i, ari - t1r - t2i + t3r);
    }
}

// ---------------- K2: segment overlap-add + envelope normalize + trim ----------------
// out[b, 512(s-2)+r] = sum_q contrib[b, s-q, 512q+r] / max(sum_q wsq[512q+r], 1e-8)
__global__ __launch_bounds__(256) void ola_kernel(const float* __restrict__ contrib,
                                                  const float* __restrict__ wsq,
                                                  float* __restrict__ out) {
    const int blk = blockIdx.x;
    const int b = blk / NSEG;
    const int s = blk - b * NSEG + 2;          // 2..2048
    const int r = threadIdx.x << 1;            // 0,2,..,510
    const float* crow = contrib + (size_t)b * NT * NFFT;
    const int qlo = (s > 2047) ? (s - 2047) : 0;
    const int qhi = (s < 3) ? s : 3;
    float ax = 0.0f, ay = 0.0f, wx = 0.0f, wy = 0.0f;
    for (int q = qlo; q <= qhi; ++q) {
        const float2 c = *(const float2*)&crow[(size_t)(s - q) * NFFT + (q << 9) + r];
        const float2 w = *(const float2*)&wsq[(q << 9) + r];
        ax += c.x; ay += c.y;
        wx += w.x; wy += w.y;
    }
    float2 o;
    o.x = ax / fmaxf(wx, 1e-8f);
    o.y = ay / fmaxf(wy, 1e-8f);
    *(float2*)&out[(size_t)b * ORIG_LEN + (size_t)(s - 2) * HOP + r] = o;
}

extern "C" void kernel_launch(void* const* d_in, const int* in_sizes, int n_in,
                              void* d_out, int out_size, void* d_ws, size_t ws_size,
                              hipStream_t stream) {
    const float* stft = (const float*)d_in[0];   // [8,1025,2048,2] f32
    const float* wsq  = (const float*)d_in[2];   // [2048] f32
    float* contrib = (float*)d_ws;               // [8,2048,2048] f32 = 128 MiB scratch
    float* out = (float*)d_out;                  // [8,1048064] f32

    istft_fft_kernel<<<NB * NT, 256, 0, stream>>>(stft, contrib);
    ola_kernel<<<NB * NSEG, 256, 0, stream>>>(contrib, wsq, out);
}

// Round 3
// 293.737 us; speedup vs baseline: 1.2721x; 1.2427x over previous
//
#include <hip/hip_runtime.h>
#include <math.h>

#define NFREQ 1025
#define NT 2048
#define NB 8
#define ORIG_LEN 1048064
#define FR 16          // frames per block (13 segments + 3 halo)
#define SEGS 13
#define NBLK 158       // ceil(2047 segments / 13)
#define FSTR 1028      // floats per frame row (16B-aligned rows, bank-friendly)
#define IOFF (FR * FSTR)

// XOR swizzle within a 1024-element frame: bijective, keeps 4-aligned groups
__device__ __forceinline__ int dphys(int m) {
    return m ^ ((((m >> 5) ^ (m >> 8)) & 7) << 2);
}
// additive pad for the twiddle table
__device__ __forceinline__ int tphys(int r) { return r + (r >> 4); }

// one radix-4 DIT stage (inverse, e^{+} twiddles), 4 butterflies per lane, in place
template <int LEN, int TSTEP>
__device__ __forceinline__ void r4stage(float* __restrict__ Rw, float* __restrict__ Iw,
                                        const float* __restrict__ TWR,
                                        const float* __restrict__ TWI, int lane) {
#pragma unroll
    for (int c = 0; c < 4; ++c) {
        const int i = lane + (c << 6);          // butterfly index in [0,256)
        const int quarter = LEN >> 2;
        const int grp = i / quarter, pos = i - grp * quarter;
        const int i0 = grp * LEN + pos;
        const int ia = dphys(i0), ib = dphys(i0 + quarter);
        const int ic = dphys(i0 + 2 * quarter), id = dphys(i0 + 3 * quarter);
        const float arr = Rw[ia], ari = Iw[ia];
        const float brr = Rw[ib], bri = Iw[ib];
        const float crr = Rw[ic], cri = Iw[ic];
        const float drr = Rw[id], dri = Iw[id];
        const int j1 = tphys(pos * TSTEP), j2 = tphys(2 * pos * TSTEP), j3 = tphys(3 * pos * TSTEP);
        const float w1r = TWR[j1], w1i = TWI[j1];
        const float w2r = TWR[j2], w2i = TWI[j2];
        const float w3r = TWR[j3], w3i = TWI[j3];
        const float t1r = brr * w1r - bri * w1i, t1i = brr * w1i + bri * w1r;
        const float t2r = crr * w2r - cri * w2i, t2i = crr * w2i + cri * w2r;
        const float t3r = drr * w3r - dri * w3i, t3i = drr * w3i + dri * w3r;
        Rw[ia] = arr + t1r + t2r + t3r;  Iw[ia] = ari + t1i + t2i + t3i;
        Rw[ib] = arr - t1i - t2r + t3i;  Iw[ib] = ari + t1r - t2i - t3r;
        Rw[ic] = arr - t1r + t2r - t3r;  Iw[ic] = ari - t1i + t2i - t3i;
        Rw[id] = arr + t1i - t2r - t3i;  Iw[id] = ari - t1r - t2i + t3r;
    }
}

__global__ __launch_bounds__(1024) void istft_fused(const float* __restrict__ in,
                                                    const float* __restrict__ wsq,
                                                    float* __restrict__ out) {
    __shared__ float D[2 * FR * FSTR];   // Re at [0, IOFF), Im at [IOFF, 2*IOFF)
    __shared__ float TWR[816], TWI[816]; // e^{+2pi i r/1024}, r in [0,768), padded
    __shared__ float WS[2048];           // window^2
    const int tid = threadIdx.x;
    const int lane = tid & 63, wv = tid >> 6;
    const int g = blockIdx.x, b = blockIdx.y;
    const int f0 = (g == 0) ? 0 : (13 * g - 1);       // first staged frame
    const int sbase = 2 + 13 * g;                     // first output segment
    const int nseg = (2049 - sbase < SEGS) ? (2049 - sbase) : SEGS;

    if (tid < 768) {
        float s, c;
        sincosf(6.28318530717958647692f * (float)tid * (1.0f / 1024.0f), &s, &c);
        const int p = tphys(tid);
        TWR[p] = c; TWI[p] = s;
    }
    for (int i = tid; i < 2048; i += 1024) WS[i] = wsq[i];

    // ---- stage 16 frames' spectra into LDS, transposed (coalesced 128B per k) ----
    const float* bbase = in + (size_t)b * NFREQ * (NT * 2);
#pragma unroll
    for (int it = 0; it < 17; ++it) {
        const int idx = tid + (it << 10);
        if (idx < FR * NFREQ) {
            const int k = idx >> 4, jf = idx & 15, ft = f0 + jf;
            float2 v = make_float2(0.0f, 0.0f);
            if (ft < NT) v = *(const float2*)(bbase + ((size_t)k * NT + ft) * 2);
            D[jf * FSTR + k] = v.x;
            D[IOFF + jf * FSTR + k] = v.y;
        }
    }
    __syncthreads();

    // ---- per-wave 1024-pt inverse FFT of frame `wv` (wave-local, no barriers) ----
    float* Rw = D + wv * FSTR;
    float* Iw = D + IOFF + wv * FSTR;

    // pack (real-FFT fold): all reads before all writes (wave-lockstep safe)
    float vr[16], vi[16];
#pragma unroll
    for (int m = 0; m < 16; ++m) {
        const int jc = lane + (m << 6);
        const float Xr = Rw[jc];
        const float Xi = (jc == 0) ? 0.0f : Iw[jc];
        const float Cr = Rw[1024 - jc];
        const float Ci = (jc == 0) ? 0.0f : -Iw[1024 - jc];
        const float ar = Xr + Cr, ai = Xi + Ci;
        const float dr = Xr - Cr, di = Xi - Ci;
        const int rr = jc >> 1;
        const int pp = tphys(rr);
        float pr = TWR[pp], pi = TWI[pp];
        if (jc & 1) {  // half-angle step: e^{i pi/1024}
            const float c1r = 0.99999529380957617f, c1i = 0.00306795676296598f;
            const float nr = pr * c1r - pi * c1i;
            pi = pr * c1i + pi * c1r; pr = nr;
        }
        const float br = dr * pr - di * pi;
        const float bi = dr * pi + di * pr;
        vr[m] = (ar - bi) * (1.0f / 2048.0f);
        vi[m] = (ai + br) * (1.0f / 2048.0f);
    }
    // stage 1 (twiddle-free) + digit-reversed placement
#pragma unroll
    for (int m0 = 0; m0 < 4; ++m0) {
        const float v0r = vr[m0], v0i = vi[m0];
        const float v1r = vr[m0 + 4], v1i = vi[m0 + 4];
        const float v2r = vr[m0 + 8], v2i = vi[m0 + 8];
        const float v3r = vr[m0 + 12], v3i = vi[m0 + 12];
        const int jb = lane + (m0 << 6);
        const int g8 = ((jb & 3) << 6) | (((jb >> 2) & 3) << 4) |
                       (((jb >> 4) & 3) << 2) | ((jb >> 6) & 3);
        const int p4 = dphys(g8 << 2);
        *(float4*)&Rw[p4] = make_float4(v0r + v1r + v2r + v3r,
                                        v0r - v1i - v2r + v3i,
                                        v0r - v1r + v2r - v3r,
                                        v0r + v1i - v2r - v3i);
        *(float4*)&Iw[p4] = make_float4(v0i + v1i + v2i + v3i,
                                        v0i + v1r - v2i - v3r,
                                        v0i - v1i + v2i - v3i,
                                        v0i - v1r - v2i + v3r);
    }
    r4stage<16, 64>(Rw, Iw, TWR, TWI, lane);
    r4stage<64, 16>(Rw, Iw, TWR, TWI, lane);
    r4stage<256, 4>(Rw, Iw, TWR, TWI, lane);
    r4stage<1024, 1>(Rw, Iw, TWR, TWI, lane);
    __syncthreads();

    // ---- overlap-add + envelope normalize + trim, straight from LDS ----
    // segment s, offset r: out = sum_q frame[s-q][512q+r] / max(sum_q ws[512q+r],1e-8)
    const int nsamp = nseg << 9;
    float* outb = out + (size_t)b * ORIG_LEN + (size_t)(sbase - 2) * 512;
#pragma unroll
    for (int it = 0; it < 7; ++it) {
        const int idx = tid + (it << 10);
        if (idx < nsamp) {
            const int seg = idx >> 9, r = idx & 511;
            const int s = sbase + seg;
            const int qlo = (s == 2048) ? 1 : 0;
            const int qhi = (s == 2) ? 2 : 3;
            float acc = 0.0f, wacc = 0.0f;
            const int po = (r & 1) ? IOFF : 0;
#pragma unroll
            for (int q = 0; q < 4; ++q) {
                if (q >= qlo && q <= qhi) {
                    const int lf = s - q - f0;              // in [0, FR)
                    const int n = (q << 9) + r;             // sample within frame
                    acc += D[po + lf * FSTR + dphys(n >> 1)];
                    wacc += WS[n];
                }
            }
            outb[idx] = acc / fmaxf(wacc, 1e-8f);
        }
    }
}

extern "C" void kernel_launch(void* const* d_in, const int* in_sizes, int n_in,
                              void* d_out, int out_size, void* d_ws, size_t ws_size,
                              hipStream_t stream) {
    const float* stft = (const float*)d_in[0];   // [8,1025,2048,2] f32
    const float* wsq  = (const float*)d_in[2];   // [2048] f32
    float* out = (float*)d_out;                  // [8,1048064] f32
    dim3 grid(NBLK, NB);
    istft_fused<<<grid, 1024, 0, stream>>>(stft, wsq, out);
}

// Round 4
// 291.639 us; speedup vs baseline: 1.2812x; 1.0072x over previous
//
#include <hip/hip_runtime.h>
#include <math.h>

#define NFREQ 1025
#define NT 2048
#define NB 8
#define ORIG_LEN 1048064
#define FR 16          // frames per block (13 segments + 3 halo)
#define SEGS 13
#define NBLK 158       // ceil(2047 segments / 13)
#define CROW 1026      // complex (float2) stride per frame row
#define PI_F 3.14159265358979323846f

// swizzle on COMPLEX index: flips bits 2-4 by higher bits; bijective involution,
// keeps aligned quads (4 complex) contiguous and in order.
__device__ __forceinline__ int cphys(int m) {
    return m ^ ((((m >> 5) ^ (m >> 8)) & 7) << 2);
}
// additive pad for the twiddle table (complex-indexed)
__device__ __forceinline__ int tphys(int r) { return r + (r >> 4); }

__device__ __forceinline__ float2 cmul(float2 a, float2 b) {
    return make_float2(a.x * b.x - a.y * b.y, a.x * b.y + a.y * b.x);
}

// one radix-4 DIT stage (inverse, e^{+} twiddles), 4 butterflies/lane, in place.
// Only w1 comes from LDS; w2 = w1^2, w3 = w1*w2 in registers.
template <int LEN, int TSTEP>
__device__ __forceinline__ void r4stage(float2* __restrict__ W,
                                        const float2* __restrict__ TW, int lane) {
#pragma unroll
    for (int c = 0; c < 4; ++c) {
        const int i = lane + (c << 6);          // butterfly index in [0,256)
        const int quarter = LEN >> 2;
        const int grp = i / quarter, pos = i - grp * quarter;
        const int i0 = grp * LEN + pos;
        const int ia = cphys(i0), ib = cphys(i0 + quarter);
        const int ic = cphys(i0 + 2 * quarter), id = cphys(i0 + 3 * quarter);
        const float2 a = W[ia], bv = W[ib], cv = W[ic], dv = W[id];
        const float2 w1 = TW[tphys(pos * TSTEP)];
        const float2 w2 = cmul(w1, w1);
        const float2 w3 = cmul(w2, w1);
        const float2 t1 = cmul(bv, w1);
        const float2 t2 = cmul(cv, w2);
        const float2 t3 = cmul(dv, w3);
        W[ia] = make_float2(a.x + t1.x + t2.x + t3.x, a.y + t1.y + t2.y + t3.y);
        W[ib] = make_float2(a.x - t1.y - t2.x + t3.y, a.y + t1.x - t2.y - t3.x);
        W[ic] = make_float2(a.x - t1.x + t2.x - t3.x, a.y - t1.y + t2.y - t3.y);
        W[id] = make_float2(a.x + t1.y - t2.x - t3.y, a.y - t1.x - t2.y + t3.x);
    }
}

__global__ __launch_bounds__(1024) void istft_fused(const float* __restrict__ in,
                                                    float* __restrict__ out) {
    __shared__ float2 D[FR * CROW];   // 16 frames x 1026 complex = 131328 B
    __shared__ float2 TW[544];        // e^{+2pi i r/1024}, r in [0,512), padded
    const int tid = threadIdx.x;
    const int lane = tid & 63, wv = tid >> 6;
    const int g = blockIdx.x, b = blockIdx.y;
    const int f0 = (g == 0) ? 0 : (13 * g - 1);       // first staged frame
    const int sbase = 2 + 13 * g;                     // first output segment
    const int nseg = (2049 - sbase < SEGS) ? (2049 - sbase) : SEGS;

    if (tid < 512) {
        float s, c;
        sincosf(6.28318530717958647692f * (float)tid * (1.0f / 1024.0f), &s, &c);
        TW[tphys(tid)] = make_float2(c, s);
    }

    // ---- stage 16 frames' spectra into LDS, transposed (coalesced per k) ----
    const float* bbase = in + (size_t)b * NFREQ * (NT * 2);
#pragma unroll
    for (int it = 0; it < 17; ++it) {
        const int idx = tid + (it << 10);
        if (idx < FR * NFREQ) {
            const int k = idx >> 4, jf = idx & 15, ft = f0 + jf;
            float2 v2 = make_float2(0.0f, 0.0f);
            if (ft < NT) v2 = *(const float2*)(bbase + ((size_t)k * NT + ft) * 2);
            D[jf * CROW + k] = v2;   // raw (unswizzled) slots, incl. Nyquist at 1024
        }
    }
    __syncthreads();

    // ---- per-wave 1024-pt inverse FFT of frame `wv` (wave-local, no barriers) ----
    float2* W = D + wv * CROW;

    // pack (real-FFT fold): reads raw slots, all reads precede all writes
    float2 v[16];
#pragma unroll
    for (int m = 0; m < 16; ++m) {
        const int jc = lane + (m << 6);
        const float2 xa = W[jc];
        const float2 xb = W[1024 - jc];
        const float Xr = xa.x, Xi = (jc == 0) ? 0.0f : xa.y;
        const float Cr = xb.x, Ci = (jc == 0) ? 0.0f : -xb.y;
        const float ar = Xr + Cr, ai = Xi + Ci;
        const float dr = Xr - Cr, di = Xi - Ci;
        float2 w = TW[tphys(jc >> 1)];
        if (jc & 1)  // half-angle step e^{+i pi/1024}
            w = cmul(w, make_float2(0.99999529380957617f, 0.00306795676296598f));
        const float br = dr * w.x - di * w.y;
        const float bi = dr * w.y + di * w.x;
        v[m] = make_float2((ar - bi) * (1.0f / 2048.0f), (ai + br) * (1.0f / 2048.0f));
    }
    // stage 1 (twiddle-free) + digit-reversed placement, 2x b128 per quad
#pragma unroll
    for (int m0 = 0; m0 < 4; ++m0) {
        const float2 v0 = v[m0], v1 = v[m0 + 4], v2 = v[m0 + 8], v3 = v[m0 + 12];
        const int jb = lane + (m0 << 6);
        const int g8 = ((jb & 3) << 6) | (((jb >> 2) & 3) << 4) |
                       (((jb >> 4) & 3) << 2) | ((jb >> 6) & 3);
        const int p4 = cphys(g8 << 2);           // quad stays contiguous & aligned
        *(float4*)&W[p4]     = make_float4(v0.x + v1.x + v2.x + v3.x,
                                           v0.y + v1.y + v2.y + v3.y,
                                           v0.x - v1.y - v2.x + v3.y,
                                           v0.y + v1.x - v2.y - v3.x);
        *(float4*)&W[p4 + 2] = make_float4(v0.x - v1.x + v2.x - v3.x,
                                           v0.y - v1.y + v2.y - v3.y,
                                           v0.x + v1.y - v2.x - v3.y,
                                           v0.y - v1.x - v2.y + v3.x);
    }
    r4stage<16, 64>(W, TW, lane);
    r4stage<64, 16>(W, TW, lane);
    r4stage<256, 4>(W, TW, lane);
    r4stage<1024, 1>(W, TW, lane);
    __syncthreads();

    // ---- overlap-add + analytic envelope + trim; 2 samples (one float2) per thread ----
    // interior envelope: sum_q hann^2(512q+r) == 1.5 exactly (hop = N/4)
    const int npairs = nseg << 8;
    float2* outb = (float2*)(out + (size_t)b * ORIG_LEN + (size_t)(sbase - 2) * 512);
#pragma unroll
    for (int it = 0; it < 4; ++it) {
        const int pj = tid + (it << 10);
        if (pj < npairs) {
            const int seg = pj >> 8, r2 = pj & 255;
            const int s = sbase + seg;
            const int qlo = (s == 2048) ? 1 : 0;
            const int qhi = (s == 2) ? 2 : 3;
            const int rowoff = (s - f0) * CROW;
            float ax = 0.0f, ay = 0.0f;
#pragma unroll
            for (int q = 0; q < 4; ++q) {
                if (q >= qlo && q <= qhi) {
                    const float2 c2 = D[rowoff - q * CROW + cphys((q << 8) + r2)];
                    ax += c2.x; ay += c2.y;
                }
            }
            float envx = 1.5f, envy = 1.5f;
            if (s == 2) {        // missing q=3 term: n = 1536 + r
                const int n0 = 1536 + (r2 << 1);
                const float wa = 0.5f - 0.5f * cosf((float)n0 * (PI_F / 1024.0f));
                const float wb = 0.5f - 0.5f * cosf((float)(n0 + 1) * (PI_F / 1024.0f));
                envx -= wa * wa; envy -= wb * wb;
            }
            if (s == 2048) {     // missing q=0 term: n = r
                const int n0 = r2 << 1;
                const float wa = 0.5f - 0.5f * cosf((float)n0 * (PI_F / 1024.0f));
                const float wb = 0.5f - 0.5f * cosf((float)(n0 + 1) * (PI_F / 1024.0f));
                envx -= wa * wa; envy -= wb * wb;
            }
            outb[pj] = make_float2(ax / envx, ay / envy);
        }
    }
}

extern "C" void kernel_launch(void* const* d_in, const int* in_sizes, int n_in,
                              void* d_out, int out_size, void* d_ws, size_t ws_size,
                              hipStream_t stream) {
    const float* stft = (const float*)d_in[0];   // [8,1025,2048,2] f32
    // d_in[1] (DFT kernel) and d_in[2] (window^2) unused: FFT + analytic envelope
    float* out = (float*)d_out;                  // [8,1048064] f32
    dim3 grid(NBLK, NB);
    istft_fused<<<grid, 1024, 0, stream>>>(stft, out);
}

// Round 7
// 257.044 us; speedup vs baseline: 1.4537x; 1.1346x over previous
//
#include <hip/hip_runtime.h>
#include <math.h>

#define NFREQ 1025
#define NT 2048
#define NB 8
#define ORIG_LEN 1048064
#define FR 8           // frames per block; waves per block
#define SEGS 5         // output segments per block (frames s-3..s use all 8 exactly)
#define NBLK 410       // ceil(2047 / 5)
#define CROW 1024      // complex slots per frame row (Nyquist lives in a register)
#define PI_F 3.14159265358979323846f

// swizzle on COMPLEX index: bijective involution, keeps aligned quads contiguous
__device__ __forceinline__ int cphys(int m) {
    return m ^ ((((m >> 5) ^ (m >> 8)) & 7) << 2);
}
// additive pad for the twiddle table
__device__ __forceinline__ int tphys(int r) { return r + (r >> 4); }

__device__ __forceinline__ float2 cmul(float2 a, float2 b) {
    return make_float2(a.x * b.x - a.y * b.y, a.x * b.y + a.y * b.x);
}

// one radix-4 DIT stage (inverse, e^{+} twiddles), 4 butterflies/lane, in place
template <int LEN, int TSTEP>
__device__ __forceinline__ void r4stage(float2* __restrict__ W,
                                        const float2* __restrict__ TW, int lane) {
#pragma unroll
    for (int c = 0; c < 4; ++c) {
        const int i = lane + (c << 6);
        const int quarter = LEN >> 2;
        const int grp = i / quarter, pos = i - grp * quarter;
        const int i0 = grp * LEN + pos;
        const int ia = cphys(i0), ib = cphys(i0 + quarter);
        const int ic = cphys(i0 + 2 * quarter), id = cphys(i0 + 3 * quarter);
        const float2 a = W[ia], bv = W[ib], cv = W[ic], dv = W[id];
        const float2 w1 = TW[tphys(pos * TSTEP)];
        const float2 w2 = cmul(w1, w1);
        const float2 w3 = cmul(w2, w1);
        const float2 t1 = cmul(bv, w1);
        const float2 t2 = cmul(cv, w2);
        const float2 t3 = cmul(dv, w3);
        W[ia] = make_float2(a.x + t1.x + t2.x + t3.x, a.y + t1.y + t2.y + t3.y);
        W[ib] = make_float2(a.x - t1.y - t2.x + t3.y, a.y + t1.x - t2.y - t3.x);
        W[ic] = make_float2(a.x - t1.x + t2.x - t3.x, a.y - t1.y + t2.y - t3.y);
        W[id] = make_float2(a.x + t1.y - t2.x - t3.y, a.y - t1.x - t2.y + t3.x);
    }
}

__global__ __launch_bounds__(512) void istft_fused(const float* __restrict__ in,
                                                   float* __restrict__ out) {
    __shared__ float2 D[FR * CROW];   // 64 KB
    __shared__ float2 TW[544];        // 4.25 KB
    const int tid = threadIdx.x;
    const int lane = tid & 63, wv = tid >> 6;

    // bijective XCD-chunk swizzle over g (NBLK = 410 = 8*51 + 2)
    const unsigned bid = blockIdx.x;
    const unsigned xcd = bid & 7u, jj = bid >> 3;
    const unsigned qq = NBLK >> 3, rr = NBLK & 7u;   // 51, 2
    const int g = (int)((xcd < rr ? xcd * (qq + 1) : rr * (qq + 1) + (xcd - rr) * qq) + jj);
    const int b = blockIdx.y;

    const int f0 = (g == 0) ? 0 : (SEGS * g - 1);
    const int sbase = 2 + SEGS * g;
    const int nseg = (2049 - sbase < SEGS) ? (2049 - sbase) : SEGS;

    if (tid < 512) {
        float s, c;
        sincosf(6.28318530717958647692f * (float)tid * (1.0f / 1024.0f), &s, &c);
        TW[tphys(tid)] = make_float2(c, s);
    }

    const float* bbase = in + (size_t)b * NFREQ * (NT * 2);

    // Nyquist (k = 1024) for this wave's frame: one scalar read on lane 0
    float nyq = 0.0f;
    {
        const int ftw = f0 + wv;
        if (lane == 0 && ftw < NT)
            nyq = bbase[((size_t)1024 * NT + ftw) * 2];
    }

    // ---- stage 8 frames x 1024 bins into LDS (transposed, coalesced per k) ----
    // all 16 loads issued into registers first (max memory-level parallelism)
    float2 regs[16];
#pragma unroll
    for (int it = 0; it < 16; ++it) {
        const int idx = tid + (it << 9);
        const int k = idx >> 3, jf = idx & 7, ft = f0 + jf;
        regs[it] = (ft < NT) ? *(const float2*)(bbase + ((size_t)k * NT + ft) * 2)
                             : make_float2(0.0f, 0.0f);
    }
#pragma unroll
    for (int it = 0; it < 16; ++it) {
        const int idx = tid + (it << 9);
        const int k = idx >> 3, jf = idx & 7;
        D[jf * CROW + k] = regs[it];   // raw (unswizzled) slots
    }
    __syncthreads();

    // ---- per-wave 1024-pt inverse FFT of frame `wv` (wave-local, no barriers) ----
    float2* W = D + wv * CROW;

    // pack (real-FFT fold): reads raw slots; all reads precede all writes
    float2 v[16];
#pragma unroll
    for (int m = 0; m < 16; ++m) {
        const int jc = lane + (m << 6);
        const float2 xa = W[jc];
        const float2 xb = (jc == 0) ? make_float2(nyq, 0.0f) : W[1024 - jc];
        const float Xr = xa.x, Xi = (jc == 0) ? 0.0f : xa.y;
        const float Cr = xb.x, Ci = (jc == 0) ? 0.0f : -xb.y;
        const float ar = Xr + Cr, ai = Xi + Ci;
        const float dr = Xr - Cr, di = Xi - Ci;
        float2 w = TW[tphys(jc >> 1)];
        if (jc & 1)  // half-angle step e^{+i pi/1024}
            w = cmul(w, make_float2(0.99999529380957617f, 0.00306795676296598f));
        const float br = dr * w.x - di * w.y;
        const float bi = dr * w.y + di * w.x;
        v[m] = make_float2((ar - bi) * (1.0f / 2048.0f), (ai + br) * (1.0f / 2048.0f));
    }
    // stage 1 (twiddle-free) + digit-reversed placement, 2x b128 per quad
#pragma unroll
    for (int m0 = 0; m0 < 4; ++m0) {
        const float2 v0 = v[m0], v1 = v[m0 + 4], v2 = v[m0 + 8], v3 = v[m0 + 12];
        const int jb = lane + (m0 << 6);
        const int g8 = ((jb & 3) << 6) | (((jb >> 2) & 3) << 4) |
                       (((jb >> 4) & 3) << 2) | ((jb >> 6) & 3);
        const int p4 = cphys(g8 << 2);
        *(float4*)&W[p4]     = make_float4(v0.x + v1.x + v2.x + v3.x,
                                           v0.y + v1.y + v2.y + v3.y,
                                           v0.x - v1.y - v2.x + v3.y,
                                           v0.y + v1.x - v2.y - v3.x);
        *(float4*)&W[p4 + 2] = make_float4(v0.x - v1.x + v2.x - v3.x,
                                           v0.y - v1.y + v2.y - v3.y,
                                           v0.x + v1.y - v2.x - v3.y,
                                           v0.y - v1.x - v2.y + v3.x);
    }
    r4stage<16, 64>(W, TW, lane);
    r4stage<64, 16>(W, TW, lane);
    r4stage<256, 4>(W, TW, lane);
    r4stage<1024, 1>(W, TW, lane);
    __syncthreads();

    // ---- overlap-add + analytic envelope + trim; 2 samples (one float2) per thread ----
    // interior envelope: sum_q hann^2(512q + r) == 1.5 exactly (hop = N/4)
    const int npairs = nseg << 8;
    float2* outb = (float2*)(out + (size_t)b * ORIG_LEN + (size_t)(sbase - 2) * 512);
#pragma unroll
    for (int it = 0; it < 3; ++it) {
        const int pj = tid + (it << 9);
        if (pj < npairs) {
            const int seg = pj >> 8, r2 = pj & 255;
            const int s = sbase + seg;
            const int qlo = (s == 2048) ? 1 : 0;
            const int qhi = (s == 2) ? 2 : 3;
            const int rowoff = (s - f0) * CROW;
            float ax = 0.0f, ay = 0.0f;
#pragma unroll
            for (int q = 0; q < 4; ++q) {
                if (q >= qlo && q <= qhi) {
                    const float2 c2 = D[rowoff - q * CROW + cphys((q << 8) + r2)];
                    ax += c2.x; ay += c2.y;
                }
            }
            float envx = 1.5f, envy = 1.5f;
            if (s == 2) {        // missing q=3 term: n = 1536 + r
                const int n0 = 1536 + (r2 << 1);
                const float wa = 0.5f - 0.5f * cosf((float)n0 * (PI_F / 1024.0f));
                const float wb = 0.5f - 0.5f * cosf((float)(n0 + 1) * (PI_F / 1024.0f));
                envx -= wa * wa; envy -= wb * wb;
            }
            if (s == 2048) {     // missing q=0 term: n = r
                const int n0 = r2 << 1;
                const float wa = 0.5f - 0.5f * cosf((float)n0 * (PI_F / 1024.0f));
                const float wb = 0.5f - 0.5f * cosf((float)(n0 + 1) * (PI_F / 1024.0f));
                envx -= wa * wa; envy -= wb * wb;
            }
            outb[pj] = make_float2(ax / envx, ay / envy);
        }
    }
}

extern "C" void kernel_launch(void* const* d_in, const int* in_sizes, int n_in,
                              void* d_out, int out_size, void* d_ws, size_t ws_size,
                              hipStream_t stream) {
    const float* stft = (const float*)d_in[0];   // [8,1025,2048,2] f32
    // d_in[1] (DFT kernel) and d_in[2] (window^2) unused: FFT + analytic envelope
    float* out = (float*)d_out;                  // [8,1048064] f32
    dim3 grid(NBLK, NB);
    istft_fused<<<grid, 512, 0, stream>>>(stft, out);
}